// Round 1
// baseline (9081.018 us; speedup 1.0000x reference)
//
#include <hip/hip_runtime.h>
#include <hip/hip_bf16.h>
#include <math.h>

// Problem constants
#define B_   2048
#define T_   48
#define H_   512
#define E_   256
#define V_   128
#define ENC_ 1024
#define H3_  1536   // 3*H

// ---------------------------------------------------------------------------
// Generic fp32 tiled GEMM: C[M,N] = A[M,K] @ B[K,N] (+ bias[N])
// A, B row-major. M % 64 == 0, N % 64 == 0, K % 16 == 0 (all shapes here obey).
// 64x64 tile, 256 threads, 4x4 per-thread microtile, BK=16.
// ---------------------------------------------------------------------------
constexpr int BM = 64, BN = 64, BK = 16;

__global__ __launch_bounds__(256) void gemm_f32(
    const float* __restrict__ A, const float* __restrict__ Bm,
    const float* __restrict__ bias, float* __restrict__ C,
    int M, int N, int K)
{
    __shared__ float As[BK][BM + 4];   // +4 pad keeps float4 alignment (68*4B = 17*16B)
    __shared__ float Bs[BK][BN + 4];

    const int tid = threadIdx.x;
    const int bm = blockIdx.y * BM;
    const int bn = blockIdx.x * BN;

    // per-thread 4x4 microtile coords
    const int tm = (tid >> 4) * 4;     // 0..60
    const int tn = (tid & 15) * 4;     // 0..60

    // staging load coords
    const int lmA = tid >> 2;          // 0..63
    const int lkA = (tid & 3) * 4;     // 0,4,8,12
    const int lkB = tid >> 4;          // 0..15
    const int lnB = (tid & 15) * 4;    // 0..60

    float acc[4][4] = {};

    for (int k0 = 0; k0 < K; k0 += BK) {
        float4 av  = *(const float4*)(A  + (size_t)(bm + lmA) * K + (k0 + lkA));
        float4 bv4 = *(const float4*)(Bm + (size_t)(k0 + lkB) * N + (bn + lnB));
        As[lkA + 0][lmA] = av.x;
        As[lkA + 1][lmA] = av.y;
        As[lkA + 2][lmA] = av.z;
        As[lkA + 3][lmA] = av.w;
        *(float4*)&Bs[lkB][lnB] = bv4;
        __syncthreads();

        #pragma unroll
        for (int k = 0; k < BK; ++k) {
            float4 a = *(const float4*)&As[k][tm];
            float4 b = *(const float4*)&Bs[k][tn];
            acc[0][0] += a.x * b.x; acc[0][1] += a.x * b.y; acc[0][2] += a.x * b.z; acc[0][3] += a.x * b.w;
            acc[1][0] += a.y * b.x; acc[1][1] += a.y * b.y; acc[1][2] += a.y * b.z; acc[1][3] += a.y * b.w;
            acc[2][0] += a.z * b.x; acc[2][1] += a.z * b.y; acc[2][2] += a.z * b.z; acc[2][3] += a.z * b.w;
            acc[3][0] += a.w * b.x; acc[3][1] += a.w * b.y; acc[3][2] += a.w * b.z; acc[3][3] += a.w * b.w;
        }
        __syncthreads();
    }

    #pragma unroll
    for (int r = 0; r < 4; ++r) {
        #pragma unroll
        for (int c = 0; c < 4; ++c) {
            float v = acc[r][c];
            if (bias) v += bias[bn + tn + c];
            C[(size_t)(bm + tm + r) * N + (bn + tn + c)] = v;
        }
    }
}

// ---------------------------------------------------------------------------
// GRU gate combine. LAYER==1: x-projection gathered from xe1[tgt_id] (the
// embed@k1+b trick). LAYER==2: x-projection read from gx buffer. gr holds
// h @ rk + rb (recurrent bias already added by GEMM). Keras reset_after=True,
// gate order z,r,h:  z=sig(xz+rz) r=sig(xr+rr) hh=tanh(xh + r*rh)
// masked (id==0) steps carry h. s (seq output) written only for layer 1.
// ---------------------------------------------------------------------------
__device__ __forceinline__ float sigmoidf_(float x) { return 1.0f / (1.0f + expf(-x)); }

template <int LAYER>
__global__ __launch_bounds__(256) void gru_gate(
    const int* __restrict__ tgt_ids, int t,
    const float* __restrict__ xsrc,   // LAYER1: xe1 [V,3H]; LAYER2: gx [B,3H]
    const float* __restrict__ gr,     // [B,3H]
    float* __restrict__ h,            // [B,H] in/out
    float* __restrict__ s)            // [B,H] seq output (layer 1 only)
{
    int idx = blockIdx.x * 256 + threadIdx.x;   // over B*H
    int b = idx >> 9;                            // /H_
    int i = idx & (H_ - 1);
    int id = tgt_ids[(size_t)b * T_ + t];

    float hv = h[(size_t)b * H_ + i];
    float hn = hv;
    if (id != 0) {                               // uniform per 512-thread span
        const float* xg = (LAYER == 1) ? (xsrc + (size_t)id * H3_)
                                       : (xsrc + (size_t)b * H3_);
        const float* g = gr + (size_t)b * H3_;
        float z  = sigmoidf_(xg[i]          + g[i]);
        float r  = sigmoidf_(xg[H_ + i]     + g[H_ + i]);
        float hh = tanhf(xg[2 * H_ + i] + r * g[2 * H_ + i]);
        hn = z * hv + (1.0f - z) * hh;
        h[(size_t)b * H_ + i] = hn;
    }
    if (LAYER == 1) s[(size_t)b * H_ + i] = hn;
}

// ---------------------------------------------------------------------------
// Fused vocab projection + softmax for one timestep.
// probs[b,t,:] = softmax(h2[b,:] @ Wv + bv).  One block (128 threads) per b.
// ---------------------------------------------------------------------------
__global__ __launch_bounds__(128) void out_softmax(
    const float* __restrict__ h2, const float* __restrict__ Wv,
    const float* __restrict__ bv, float* __restrict__ out, int t)
{
    const int b = blockIdx.x;
    const int v = threadIdx.x;   // 0..127

    __shared__ float hrow[H_];
    __shared__ float red[V_];

    #pragma unroll
    for (int i = v; i < H_; i += V_) hrow[i] = h2[(size_t)b * H_ + i];
    __syncthreads();

    float acc = bv[v];
    #pragma unroll 8
    for (int k = 0; k < H_; ++k) acc += hrow[k] * Wv[(size_t)k * V_ + v];

    // block max
    red[v] = acc; __syncthreads();
    for (int s = 64; s > 0; s >>= 1) {
        if (v < s) red[v] = fmaxf(red[v], red[v + s]);
        __syncthreads();
    }
    float mx = red[0]; __syncthreads();

    float e = expf(acc - mx);
    red[v] = e; __syncthreads();
    for (int s = 64; s > 0; s >>= 1) {
        if (v < s) red[v] += red[v + s];
        __syncthreads();
    }
    float sum = red[0];

    out[((size_t)b * T_ + t) * V_ + v] = e / sum;
}

// ---------------------------------------------------------------------------
// Launch
// ---------------------------------------------------------------------------
extern "C" void kernel_launch(void* const* d_in, const int* in_sizes, int n_in,
                              void* d_out, int out_size, void* d_ws, size_t ws_size,
                              hipStream_t stream)
{
    const int*   tgt  = (const int*)  d_in[0];   // [B,T]
    const float* enc  = (const float*)d_in[1];   // [B,ENC]
    const float* Wi1  = (const float*)d_in[2];   // [ENC,H]
    const float* Wi2  = (const float*)d_in[3];   // [ENC,H]
    const float* emb  = (const float*)d_in[4];   // [V,E]
    const float* k1   = (const float*)d_in[5];   // [E,3H]
    const float* rk1  = (const float*)d_in[6];   // [H,3H]
    const float* b1   = (const float*)d_in[7];   // [2,3H]
    const float* k2   = (const float*)d_in[8];   // [H,3H]
    const float* rk2  = (const float*)d_in[9];   // [H,3H]
    const float* b2   = (const float*)d_in[10];  // [2,3H]
    const float* Wv   = (const float*)d_in[11];  // [H,V]
    const float* bv   = (const float*)d_in[12];  // [V]
    float* out = (float*)d_out;

    // workspace layout (floats); total ~9.6M floats = ~39 MB
    float* ws  = (float*)d_ws;
    float* xe1 = ws;                         // [V,3H]
    float* h1  = xe1 + (size_t)V_ * H3_;     // [B,H]
    float* h2  = h1  + (size_t)B_ * H_;      // [B,H]
    float* s1  = h2  + (size_t)B_ * H_;      // [B,H]
    float* gr  = s1  + (size_t)B_ * H_;      // [B,3H]
    float* gx  = gr  + (size_t)B_ * H3_;     // [B,3H]

    dim3 blk(256);

    // xe1 = embed_table @ k1 + b1[0]   (reassociated x1 GEMM: 128x256x1536)
    gemm_f32<<<dim3(H3_ / BN, V_ / BM), blk, 0, stream>>>(emb, k1, b1, xe1, V_, H3_, E_);
    // h01 = enc @ W_init1 ; h02 = enc @ W_init2
    gemm_f32<<<dim3(H_ / BN, B_ / BM), blk, 0, stream>>>(enc, Wi1, nullptr, h1, B_, H_, ENC_);
    gemm_f32<<<dim3(H_ / BN, B_ / BM), blk, 0, stream>>>(enc, Wi2, nullptr, h2, B_, H_, ENC_);

    const dim3 gemm_grid(H3_ / BN, B_ / BM);   // 24 x 32 = 768 blocks
    const int gate_blocks = (B_ * H_) / 256;   // 4096

    for (int t = 0; t < T_; ++t) {
        // layer 1: gr = h1 @ rk1 + b1[1]
        gemm_f32<<<gemm_grid, blk, 0, stream>>>(h1, rk1, b1 + H3_, gr, B_, H3_, H_);
        gru_gate<1><<<gate_blocks, blk, 0, stream>>>(tgt, t, xe1, gr, h1, s1);

        // layer 2: gx = s1 @ k2 + b2[0] ; gr = h2 @ rk2 + b2[1]
        gemm_f32<<<gemm_grid, blk, 0, stream>>>(s1, k2, b2, gx, B_, H3_, H_);
        gemm_f32<<<gemm_grid, blk, 0, stream>>>(h2, rk2, b2 + H3_, gr, B_, H3_, H_);
        gru_gate<2><<<gate_blocks, blk, 0, stream>>>(tgt, t, gx, gr, h2, nullptr);

        // probs[:,t,:] = softmax(h2 @ Wv + bv)
        out_softmax<<<dim3(B_), dim3(V_), 0, stream>>>(h2, Wv, bv, out, t);
    }
}

// Round 2
// 4548.466 us; speedup vs baseline: 1.9965x; 1.9965x over previous
//
#include <hip/hip_runtime.h>
#include <hip/hip_bf16.h>
#include <math.h>

// Problem constants
#define B_   2048
#define T_   48
#define H_   512
#define E_   256
#define V_   128
#define ENC_ 1024
#define H3_  1536   // 3*H

typedef __attribute__((ext_vector_type(8))) short bf16x8;   // 8 bf16 = 4 VGPRs
typedef __attribute__((ext_vector_type(4))) float f32x4;
typedef unsigned short ushort_t;

#if defined(__has_builtin)
#if __has_builtin(__builtin_amdgcn_global_load_lds)
#define HAVE_ASYNC 1
#endif
#endif
#ifndef HAVE_ASYNC
#define HAVE_ASYNC 0
#endif

// ---------------------------------------------------------------------------
// fp32 tiled GEMM (setup only): C[M,N] = A[M,K] @ B[K,N] (+ bias[N])
// ---------------------------------------------------------------------------
constexpr int BM = 64, BN = 64, BK = 16;

__global__ __launch_bounds__(256) void gemm_f32(
    const float* __restrict__ A, const float* __restrict__ Bm,
    const float* __restrict__ bias, float* __restrict__ C,
    int M, int N, int K)
{
    __shared__ float As[BK][BM + 4];
    __shared__ float Bs[BK][BN + 4];

    const int tid = threadIdx.x;
    const int bm = blockIdx.y * BM;
    const int bn = blockIdx.x * BN;
    const int tm = (tid >> 4) * 4;
    const int tn = (tid & 15) * 4;
    const int lmA = tid >> 2;
    const int lkA = (tid & 3) * 4;
    const int lkB = tid >> 4;
    const int lnB = (tid & 15) * 4;

    float acc[4][4] = {};

    for (int k0 = 0; k0 < K; k0 += BK) {
        float4 av  = *(const float4*)(A  + (size_t)(bm + lmA) * K + (k0 + lkA));
        float4 bv4 = *(const float4*)(Bm + (size_t)(k0 + lkB) * N + (bn + lnB));
        As[lkA + 0][lmA] = av.x;
        As[lkA + 1][lmA] = av.y;
        As[lkA + 2][lmA] = av.z;
        As[lkA + 3][lmA] = av.w;
        *(float4*)&Bs[lkB][lnB] = bv4;
        __syncthreads();

        #pragma unroll
        for (int k = 0; k < BK; ++k) {
            float4 a = *(const float4*)&As[k][tm];
            float4 b = *(const float4*)&Bs[k][tn];
            acc[0][0] += a.x * b.x; acc[0][1] += a.x * b.y; acc[0][2] += a.x * b.z; acc[0][3] += a.x * b.w;
            acc[1][0] += a.y * b.x; acc[1][1] += a.y * b.y; acc[1][2] += a.y * b.z; acc[1][3] += a.y * b.w;
            acc[2][0] += a.z * b.x; acc[2][1] += a.z * b.y; acc[2][2] += a.z * b.z; acc[2][3] += a.z * b.w;
            acc[3][0] += a.w * b.x; acc[3][1] += a.w * b.y; acc[3][2] += a.w * b.z; acc[3][3] += a.w * b.w;
        }
        __syncthreads();
    }

    #pragma unroll
    for (int r = 0; r < 4; ++r)
        #pragma unroll
        for (int c = 0; c < 4; ++c) {
            float v = acc[r][c];
            if (bias) v += bias[bn + tn + c];
            C[(size_t)(bm + tm + r) * N + (bn + tn + c)] = v;
        }
}

// ---------------------------------------------------------------------------
// Weight transpose + bf16 convert: W[K][N] fp32 -> Wt[N][K] bf16 (one-time)
// ---------------------------------------------------------------------------
__global__ __launch_bounds__(256) void transpose_to_bf16(
    const float* __restrict__ W, __hip_bfloat16* __restrict__ Wt, int K, int N)
{
    __shared__ float tile[32][33];
    const int bk = blockIdx.y * 32, bn = blockIdx.x * 32;
    const int tx = threadIdx.x & 31, ty = threadIdx.x >> 5;  // 32x8
    #pragma unroll
    for (int i = ty; i < 32; i += 8)
        tile[i][tx] = W[(size_t)(bk + i) * N + (bn + tx)];
    __syncthreads();
    #pragma unroll
    for (int i = ty; i < 32; i += 8)
        Wt[(size_t)(bn + i) * K + (bk + tx)] = __float2bfloat16(tile[tx][i]);
}

__global__ __launch_bounds__(256) void f32_to_bf16_k(
    const float* __restrict__ a, __hip_bfloat16* __restrict__ o, int n)
{
    int idx = blockIdx.x * 256 + threadIdx.x;
    if (idx < n) o[idx] = __float2bfloat16(a[idx]);
}

// ---------------------------------------------------------------------------
// bf16 MFMA GEMM body: C[M,N] (fp32, +bias) = A[M,K] @ Bt[N,K]^T
// A row-major [M][K] bf16; Bt row-major [N][K] bf16 (i.e. B transposed).
// 128x128 tile, BK=32, 256 threads (4 waves in 2x2), 4x4 16x16 frags/wave.
// K % 32 == 0, M % 128 == 0, N % 128 == 0.
// ---------------------------------------------------------------------------
__device__ __forceinline__ void gld_lds16(const ushort_t* g, ushort_t* l)
{
#if HAVE_ASYNC
    __builtin_amdgcn_global_load_lds(
        (const __attribute__((address_space(1))) unsigned int*)g,
        (__attribute__((address_space(3))) unsigned int*)l, 16, 0, 0);
#endif
}

__device__ __forceinline__ void gemm_body(
    const ushort_t* __restrict__ A, const ushort_t* __restrict__ Bt,
    const float* __restrict__ bias, float* __restrict__ C,
    int K, int N, int m0, int n0)
{
    __shared__ __attribute__((aligned(16))) ushort_t Al[128 * 32];
    __shared__ __attribute__((aligned(16))) ushort_t Bl[128 * 32];

    const int tid  = threadIdx.x;
    const int lane = tid & 63;
    const int w    = tid >> 6;        // wave 0..3
    const int ln   = lane & 15;
    const int kg   = lane >> 4;       // 0..3
    const int wr   = w >> 1, wc = w & 1;

    // staging: chunk c = 1024B = 16 rows of 32 bf16; wave w does chunks w, w+4
    const int srow = (lane >> 2);          // 0..15 within chunk
    const int skb  = (lane & 3) * 8;       // k-element offset

    f32x4 acc[4][4] = {};

    for (int k0 = 0; k0 < K; k0 += 32) {
        const ushort_t* ga0 = A  + (size_t)(m0 + w * 16 + srow) * K + k0 + skb;
        const ushort_t* gb0 = Bt + (size_t)(n0 + w * 16 + srow) * K + k0 + skb;
#if HAVE_ASYNC
        gld_lds16(ga0,                 Al + w * 512);
        gld_lds16(ga0 + (size_t)64 * K, Al + (w + 4) * 512);
        gld_lds16(gb0,                 Bl + w * 512);
        gld_lds16(gb0 + (size_t)64 * K, Bl + (w + 4) * 512);
#else
        *(bf16x8*)(Al + w * 512 + lane * 8)       = *(const bf16x8*)ga0;
        *(bf16x8*)(Al + (w + 4) * 512 + lane * 8) = *(const bf16x8*)(ga0 + (size_t)64 * K);
        *(bf16x8*)(Bl + w * 512 + lane * 8)       = *(const bf16x8*)gb0;
        *(bf16x8*)(Bl + (w + 4) * 512 + lane * 8) = *(const bf16x8*)(gb0 + (size_t)64 * K);
#endif
        __syncthreads();

        bf16x8 af[4], bfr[4];
        #pragma unroll
        for (int fm = 0; fm < 4; ++fm)
            af[fm] = *(const bf16x8*)(Al + (wr * 64 + fm * 16 + ln) * 32 + kg * 8);
        #pragma unroll
        for (int fn = 0; fn < 4; ++fn)
            bfr[fn] = *(const bf16x8*)(Bl + (wc * 64 + fn * 16 + ln) * 32 + kg * 8);

        #pragma unroll
        for (int fm = 0; fm < 4; ++fm)
            #pragma unroll
            for (int fn = 0; fn < 4; ++fn)
                acc[fm][fn] = __builtin_amdgcn_mfma_f32_16x16x32_bf16(
                    af[fm], bfr[fn], acc[fm][fn], 0, 0, 0);
        __syncthreads();
    }

    // epilogue: C[m][n] = acc + bias[n]; row = quad*4+reg, col = ln
    #pragma unroll
    for (int fn = 0; fn < 4; ++fn) {
        const int col = n0 + wc * 64 + fn * 16 + ln;
        const float bv = bias[col];
        #pragma unroll
        for (int fm = 0; fm < 4; ++fm) {
            const int row = m0 + wr * 64 + fm * 16 + kg * 4;
            #pragma unroll
            for (int r = 0; r < 4; ++r)
                C[(size_t)(row + r) * N + col] = acc[fm][fn][r] + bv;
        }
    }
}

__global__ __launch_bounds__(256) void gemm_bf16_one(
    const ushort_t* __restrict__ A, const ushort_t* __restrict__ Bt,
    const float* __restrict__ bias, float* __restrict__ C, int K, int N)
{
    gemm_body(A, Bt, bias, C, K, N, blockIdx.y * 128, blockIdx.x * 128);
}

// two independent GEMMs in one launch (fills the CUs: 384 blocks)
__global__ __launch_bounds__(256) void gemm_bf16_dual(
    const ushort_t* __restrict__ A0, const ushort_t* __restrict__ Bt0,
    const float* __restrict__ bias0, float* __restrict__ C0,
    const ushort_t* __restrict__ A1, const ushort_t* __restrict__ Bt1,
    const float* __restrict__ bias1, float* __restrict__ C1,
    int K, int N)
{
    const int by = blockIdx.y;
    const bool second = by >= 16;
    gemm_body(second ? A1 : A0, second ? Bt1 : Bt0,
              second ? bias1 : bias0, second ? C1 : C0,
              K, N, (second ? by - 16 : by) * 128, blockIdx.x * 128);
}

// ---------------------------------------------------------------------------
// GRU gate combine (fp32 math; writes fp32 state + bf16 mirror for GEMMs)
// ---------------------------------------------------------------------------
__device__ __forceinline__ float sigmoidf_(float x) { return 1.0f / (1.0f + expf(-x)); }

template <int LAYER>
__global__ __launch_bounds__(256) void gru_gate(
    const int* __restrict__ tgt_ids, int t,
    const float* __restrict__ xsrc,   // LAYER1: xe1 [V,3H] (gather); LAYER2: gx [B,3H]
    const float* __restrict__ gr,     // [B,3H] = h @ rk + rb
    float* __restrict__ h,            // [B,H] fp32 state
    __hip_bfloat16* __restrict__ hb)  // [B,H] bf16 mirror
{
    int idx = blockIdx.x * 256 + threadIdx.x;
    int b = idx >> 9;
    int i = idx & (H_ - 1);
    int id = tgt_ids[(size_t)b * T_ + t];
    if (id == 0) return;  // masked: carry state (uniform per 512-thread span)

    const float* xg = (LAYER == 1) ? (xsrc + (size_t)id * H3_)
                                   : (xsrc + (size_t)b * H3_);
    const float* g = gr + (size_t)b * H3_;
    float hv = h[(size_t)b * H_ + i];
    float z  = sigmoidf_(xg[i]          + g[i]);
    float r  = sigmoidf_(xg[H_ + i]     + g[H_ + i]);
    float hh = tanhf(xg[2 * H_ + i] + r * g[2 * H_ + i]);
    float hn = z * hv + (1.0f - z) * hh;
    h[(size_t)b * H_ + i]  = hn;
    hb[(size_t)b * H_ + i] = __float2bfloat16(hn);
}

// ---------------------------------------------------------------------------
// Fused vocab projection + softmax (fp32). 16 rows/block, 256 threads:
// thread = (cg 0..31: 4 cols) x (rg 0..7: 2 rows). Wv float4 reads.
// ---------------------------------------------------------------------------
__device__ __forceinline__ void softmax_write4(
    float ax, float ay, float az, float aw, float* __restrict__ outp, int cg)
{
    float m = fmaxf(fmaxf(ax, ay), fmaxf(az, aw));
    #pragma unroll
    for (int d = 16; d >= 1; d >>= 1) m = fmaxf(m, __shfl_xor(m, d));
    float ex = __expf(ax - m), ey = __expf(ay - m),
          ez = __expf(az - m), ew = __expf(aw - m);
    float s = ex + ey + ez + ew;
    #pragma unroll
    for (int d = 16; d >= 1; d >>= 1) s += __shfl_xor(s, d);
    float inv = 1.0f / s;
    float4 o; o.x = ex * inv; o.y = ey * inv; o.z = ez * inv; o.w = ew * inv;
    *(float4*)(outp + cg * 4) = o;
}

__global__ __launch_bounds__(256) void out_softmax(
    const float* __restrict__ h2, const float* __restrict__ Wv,
    const float* __restrict__ bv, float* __restrict__ out, int t)
{
    const int tid = threadIdx.x;
    const int cg = tid & 31;          // cols 4cg..4cg+3
    const int rg = tid >> 5;          // rows rg*2, rg*2+1
    const int row0 = blockIdx.x * 16;

    __shared__ float hs[16][512];     // 32 KB
    for (int idx = tid; idx < 16 * 512; idx += 256)
        hs[idx >> 9][idx & 511] = h2[(size_t)(row0 + (idx >> 9)) * 512 + (idx & 511)];
    __syncthreads();

    const int r0 = rg * 2;
    const float4 bvv = *(const float4*)(bv + cg * 4);
    float a0x = bvv.x, a0y = bvv.y, a0z = bvv.z, a0w = bvv.w;
    float a1x = bvv.x, a1y = bvv.y, a1z = bvv.z, a1w = bvv.w;

    #pragma unroll 4
    for (int k = 0; k < 512; ++k) {
        float4 wv = *(const float4*)(Wv + (size_t)k * V_ + cg * 4);
        float h0 = hs[r0][k], h1 = hs[r0 + 1][k];
        a0x += h0 * wv.x; a0y += h0 * wv.y; a0z += h0 * wv.z; a0w += h0 * wv.w;
        a1x += h1 * wv.x; a1y += h1 * wv.y; a1z += h1 * wv.z; a1w += h1 * wv.w;
    }

    softmax_write4(a0x, a0y, a0z, a0w, out + ((size_t)(row0 + r0) * T_ + t) * V_, cg);
    softmax_write4(a1x, a1y, a1z, a1w, out + ((size_t)(row0 + r0 + 1) * T_ + t) * V_, cg);
}

// ---------------------------------------------------------------------------
// Launch
// ---------------------------------------------------------------------------
extern "C" void kernel_launch(void* const* d_in, const int* in_sizes, int n_in,
                              void* d_out, int out_size, void* d_ws, size_t ws_size,
                              hipStream_t stream)
{
    const int*   tgt  = (const int*)  d_in[0];
    const float* enc  = (const float*)d_in[1];
    const float* Wi1  = (const float*)d_in[2];
    const float* Wi2  = (const float*)d_in[3];
    const float* emb  = (const float*)d_in[4];
    const float* k1   = (const float*)d_in[5];
    const float* rk1  = (const float*)d_in[6];
    const float* b1   = (const float*)d_in[7];
    const float* k2   = (const float*)d_in[8];
    const float* rk2  = (const float*)d_in[9];
    const float* b2   = (const float*)d_in[10];
    const float* Wv   = (const float*)d_in[11];
    const float* bv   = (const float*)d_in[12];
    float* out = (float*)d_out;

    // workspace layout  (~41 MB)
    float* ws  = (float*)d_ws;
    float* xe1 = ws;                          // [V,3H]
    float* h1f = xe1 + (size_t)V_ * H3_;      // [B,H]  (h1f,h2f contiguous)
    float* h2f = h1f + (size_t)B_ * H_;       // [B,H]
    float* gr  = h2f + (size_t)B_ * H_;       // [B,3H]
    float* gx  = gr  + (size_t)B_ * H3_;      // [B,3H]
    __hip_bfloat16* h1b  = (__hip_bfloat16*)(gx + (size_t)B_ * H3_);  // [B,H] (h1b,h2b contiguous)
    __hip_bfloat16* h2b  = h1b  + (size_t)B_ * H_;
    __hip_bfloat16* rk1t = h2b  + (size_t)B_ * H_;    // [3H,H] = rk1^T
    __hip_bfloat16* k2t  = rk1t + (size_t)H3_ * H_;   // [3H,H] = k2^T
    __hip_bfloat16* rk2t = k2t  + (size_t)H3_ * H_;   // [3H,H] = rk2^T

    dim3 blk(256);

    // one-time: weight transposes to bf16
    transpose_to_bf16<<<dim3(H3_ / 32, H_ / 32), blk, 0, stream>>>(rk1, rk1t, H_, H3_);
    transpose_to_bf16<<<dim3(H3_ / 32, H_ / 32), blk, 0, stream>>>(k2,  k2t,  H_, H3_);
    transpose_to_bf16<<<dim3(H3_ / 32, H_ / 32), blk, 0, stream>>>(rk2, rk2t, H_, H3_);

    // xe1 = embed_table @ k1 + b1[0]   (reassociated x1; gathered per (b,t))
    gemm_f32<<<dim3(H3_ / BN, V_ / BM), blk, 0, stream>>>(emb, k1, b1, xe1, V_, H3_, E_);
    // h01 = enc @ W_init1 ; h02 = enc @ W_init2  (fp32 for precision)
    gemm_f32<<<dim3(H_ / BN, B_ / BM), blk, 0, stream>>>(enc, Wi1, nullptr, h1f, B_, H_, ENC_);
    gemm_f32<<<dim3(H_ / BN, B_ / BM), blk, 0, stream>>>(enc, Wi2, nullptr, h2f, B_, H_, ENC_);
    // bf16 mirrors of h1,h2 (contiguous pair)
    f32_to_bf16_k<<<(2 * B_ * H_) / 256, blk, 0, stream>>>(h1f, h1b, 2 * B_ * H_);

    const int gate_blocks = (B_ * H_) / 256;   // 4096

    for (int t = 0; t < T_; ++t) {
        // layer 1 recurrent: gr = h1 @ rk1 + b1[1]
        gemm_bf16_one<<<dim3(H3_ / 128, B_ / 128), blk, 0, stream>>>(
            (const ushort_t*)h1b, (const ushort_t*)rk1t, b1 + H3_, gr, H_, H3_);
        gru_gate<1><<<gate_blocks, blk, 0, stream>>>(tgt, t, xe1, gr, h1f, h1b);

        // layer 2: gx = seq1 @ k2 + b2[0]  and  gr = h2 @ rk2 + b2[1]  (fused)
        gemm_bf16_dual<<<dim3(H3_ / 128, 2 * B_ / 128), blk, 0, stream>>>(
            (const ushort_t*)h1b, (const ushort_t*)k2t,  b2,       gx,
            (const ushort_t*)h2b, (const ushort_t*)rk2t, b2 + H3_, gr, H_, H3_);
        gru_gate<2><<<gate_blocks, blk, 0, stream>>>(tgt, t, gx, gr, h2f, h2b);

        // probs[:,t,:] = softmax(h2 @ Wv + bv)  (fp32 path)
        out_softmax<<<dim3(B_ / 16), blk, 0, stream>>>(h2f, Wv, bv, out, t);
    }
}

// Round 3
// 4462.434 us; speedup vs baseline: 2.0350x; 1.0193x over previous
//
#include <hip/hip_runtime.h>
#include <hip/hip_bf16.h>
#include <math.h>

// Problem constants
#define B_   2048
#define T_   48
#define H_   512
#define E_   256
#define V_   128
#define ENC_ 1024
#define H3_  1536   // 3*H
#define BH_  (B_ * H_)

typedef __attribute__((ext_vector_type(8))) short bf16x8;   // 8 bf16 = 4 VGPRs
typedef __attribute__((ext_vector_type(4))) float f32x4;
typedef unsigned short ushort_t;

#if defined(__has_builtin)
#if __has_builtin(__builtin_amdgcn_global_load_lds)
#define HAVE_ASYNC 1
#endif
#endif
#ifndef HAVE_ASYNC
#define HAVE_ASYNC 0
#endif

__device__ __forceinline__ void gld_lds16(const ushort_t* g, ushort_t* l)
{
#if HAVE_ASYNC
    __builtin_amdgcn_global_load_lds(
        (const __attribute__((address_space(1))) unsigned int*)g,
        (__attribute__((address_space(3))) unsigned int*)l, 16, 0, 0);
#endif
}

__device__ __forceinline__ float sigmoidf_(float x) { return 1.0f / (1.0f + expf(-x)); }

// ---------------------------------------------------------------------------
// fp32 tiled GEMM (setup only): C[M,N] = A[M,K] @ B[K,N] (+ bias[N])
// ---------------------------------------------------------------------------
constexpr int BM = 64, BN = 64, BK = 16;

__global__ __launch_bounds__(256) void gemm_f32(
    const float* __restrict__ A, const float* __restrict__ Bm,
    const float* __restrict__ bias, float* __restrict__ C,
    int M, int N, int K)
{
    __shared__ float As[BK][BM + 4];
    __shared__ float Bs[BK][BN + 4];

    const int tid = threadIdx.x;
    const int bm = blockIdx.y * BM;
    const int bn = blockIdx.x * BN;
    const int tm = (tid >> 4) * 4;
    const int tn = (tid & 15) * 4;
    const int lmA = tid >> 2;
    const int lkA = (tid & 3) * 4;
    const int lkB = tid >> 4;
    const int lnB = (tid & 15) * 4;

    float acc[4][4] = {};

    for (int k0 = 0; k0 < K; k0 += BK) {
        float4 av  = *(const float4*)(A  + (size_t)(bm + lmA) * K + (k0 + lkA));
        float4 bv4 = *(const float4*)(Bm + (size_t)(k0 + lkB) * N + (bn + lnB));
        As[lkA + 0][lmA] = av.x;
        As[lkA + 1][lmA] = av.y;
        As[lkA + 2][lmA] = av.z;
        As[lkA + 3][lmA] = av.w;
        *(float4*)&Bs[lkB][lnB] = bv4;
        __syncthreads();

        #pragma unroll
        for (int k = 0; k < BK; ++k) {
            float4 a = *(const float4*)&As[k][tm];
            float4 b = *(const float4*)&Bs[k][tn];
            acc[0][0] += a.x * b.x; acc[0][1] += a.x * b.y; acc[0][2] += a.x * b.z; acc[0][3] += a.x * b.w;
            acc[1][0] += a.y * b.x; acc[1][1] += a.y * b.y; acc[1][2] += a.y * b.z; acc[1][3] += a.y * b.w;
            acc[2][0] += a.z * b.x; acc[2][1] += a.z * b.y; acc[2][2] += a.z * b.z; acc[2][3] += a.z * b.w;
            acc[3][0] += a.w * b.x; acc[3][1] += a.w * b.y; acc[3][2] += a.w * b.z; acc[3][3] += a.w * b.w;
        }
        __syncthreads();
    }

    #pragma unroll
    for (int r = 0; r < 4; ++r)
        #pragma unroll
        for (int c = 0; c < 4; ++c) {
            float v = acc[r][c];
            if (bias) v += bias[bn + tn + c];
            C[(size_t)(bm + tm + r) * N + (bn + tn + c)] = v;
        }
}

// ---------------------------------------------------------------------------
// Weight transpose + bf16 convert: W[K][N] fp32 -> Wt[N][K] bf16 (one-time)
// ---------------------------------------------------------------------------
__global__ __launch_bounds__(256) void transpose_to_bf16(
    const float* __restrict__ W, __hip_bfloat16* __restrict__ Wt, int K, int N)
{
    __shared__ float tile[32][33];
    const int bk = blockIdx.y * 32, bn = blockIdx.x * 32;
    const int tx = threadIdx.x & 31, ty = threadIdx.x >> 5;
    #pragma unroll
    for (int i = ty; i < 32; i += 8)
        tile[i][tx] = W[(size_t)(bk + i) * N + (bn + tx)];
    __syncthreads();
    #pragma unroll
    for (int i = ty; i < 32; i += 8)
        Wt[(size_t)(bn + i) * K + (bk + tx)] = __float2bfloat16(tile[tx][i]);
}

__global__ __launch_bounds__(256) void f32_to_bf16_k(
    const float* __restrict__ a, __hip_bfloat16* __restrict__ o, int n)
{
    int idx = blockIdx.x * 256 + threadIdx.x;
    if (idx < n) o[idx] = __float2bfloat16(a[idx]);
}

// ---------------------------------------------------------------------------
// Layer-1 fused: per block, 128 batch rows x 32 hidden units (all 3 gates).
// acc[g] = h1_cur[128xK] @ rk1t[gate g strip, 32xK]^T, then full GRU gate math
// with xe1[tgt_id] gather in epilogue. Writes h1f/h1b (ping-pong).
// Waves 2x2: wr in rows (64 each, 4 frags), wc in i (16 each), 3 gates.
// ---------------------------------------------------------------------------
__global__ __launch_bounds__(256, 2) void l1_fused(
    const int* __restrict__ tgt, int t,
    const float* __restrict__ xe1,            // [V,3H] embed@k1 + b1[0]
    const ushort_t* __restrict__ rkt,         // [3H,H] rk1^T bf16
    const float* __restrict__ rb,             // b1[1] (recurrent bias, 3H)
    const float* __restrict__ hf_cur, const ushort_t* __restrict__ hb_cur,
    float* __restrict__ hf_nxt, __hip_bfloat16* __restrict__ hb_nxt)
{
    __shared__ __attribute__((aligned(16))) ushort_t Al[128 * 32];  // 8 KB
    __shared__ __attribute__((aligned(16))) ushort_t Bl[3 * 32 * 32]; // 6 KB

    const int tid  = threadIdx.x;
    const int lane = tid & 63;
    const int w    = tid >> 6;
    const int ln   = lane & 15;
    const int kg   = lane >> 4;
    const int wr   = w >> 1, wc = w & 1;

    const int m0 = blockIdx.y * 128;
    const int i0 = blockIdx.x * 32;

    const int crow = lane >> 2;          // row within 16-row chunk
    const int ckof = (lane & 3) * 8;     // k element offset within 32

    f32x4 acc[4][3] = {};

    for (int k0 = 0; k0 < H_; k0 += 32) {
        // stage 14 chunks (8 A + 6 B), wave w takes c = w, w+4, ...
        #pragma unroll
        for (int c = w; c < 14; c += 4) {
            const ushort_t* g;
            ushort_t* l;
            if (c < 8) {
                g = hb_cur + (size_t)(m0 + c * 16 + crow) * H_ + k0 + ckof;
                l = Al + c * 512;
            } else {
                const int idx = c - 8;           // strip g = idx>>1, half = idx&1
                g = rkt + (size_t)((idx >> 1) * H_ + i0 + (idx & 1) * 16 + crow) * H_ + k0 + ckof;
                l = Bl + idx * 512;
            }
#if HAVE_ASYNC
            gld_lds16(g, l);
#else
            *(bf16x8*)(l + lane * 8) = *(const bf16x8*)g;
#endif
        }
        __syncthreads();

        bf16x8 af[4], bf[3];
        #pragma unroll
        for (int fm = 0; fm < 4; ++fm)
            af[fm] = *(const bf16x8*)(Al + (wr * 64 + fm * 16 + ln) * 32 + kg * 8);
        #pragma unroll
        for (int g = 0; g < 3; ++g)
            bf[g] = *(const bf16x8*)(Bl + g * 1024 + (wc * 16 + ln) * 32 + kg * 8);

        #pragma unroll
        for (int fm = 0; fm < 4; ++fm)
            #pragma unroll
            for (int g = 0; g < 3; ++g)
                acc[fm][g] = __builtin_amdgcn_mfma_f32_16x16x32_bf16(
                    af[fm], bf[g], acc[fm][g], 0, 0, 0);
        __syncthreads();
    }

    // epilogue: full GRU gate math; i is fixed per thread
    const int i = i0 + wc * 16 + ln;
    const float rbz = rb[i], rbr = rb[H_ + i], rbh = rb[2 * H_ + i];

    #pragma unroll
    for (int fm = 0; fm < 4; ++fm) {
        #pragma unroll
        for (int r = 0; r < 4; ++r) {
            const int b = m0 + wr * 64 + fm * 16 + kg * 4 + r;
            const int id = tgt[(size_t)b * T_ + t];
            const float* xg = xe1 + (size_t)id * H3_;
            const float hv = hf_cur[(size_t)b * H_ + i];
            float z  = sigmoidf_(xg[i]          + acc[fm][0][r] + rbz);
            float rr = sigmoidf_(xg[H_ + i]     + acc[fm][1][r] + rbr);
            float hh = tanhf(xg[2 * H_ + i] + rr * (acc[fm][2][r] + rbh));
            float hn = (id != 0) ? (z * hv + (1.0f - z) * hh) : hv;
            hf_nxt[(size_t)b * H_ + i] = hn;
            hb_nxt[(size_t)b * H_ + i] = __float2bfloat16(hn);
        }
    }
}

// ---------------------------------------------------------------------------
// Layer-2 fused: both GEMMs (x = s1@k2, rec = h2@rk2) + gate math.
// Same tiling: 128 rows x 32 i x 3 gates, but x2 matrices.
// ---------------------------------------------------------------------------
__global__ __launch_bounds__(256, 2) void l2_fused(
    const int* __restrict__ tgt, int t,
    const ushort_t* __restrict__ k2t,         // [3H,H] k2^T bf16
    const ushort_t* __restrict__ rk2t,        // [3H,H] rk2^T bf16
    const float* __restrict__ bx,             // b2[0]
    const float* __restrict__ br,             // b2[1]
    const ushort_t* __restrict__ s1b,         // [B,H] seq1 (h1b_nxt)
    const float* __restrict__ hf_cur, const ushort_t* __restrict__ hb_cur,
    float* __restrict__ hf_nxt, __hip_bfloat16* __restrict__ hb_nxt)
{
    __shared__ __attribute__((aligned(16))) ushort_t lds[14336];  // 28 KB
    ushort_t* A0l = lds;               // s1 tile   128x32
    ushort_t* A1l = lds + 4096;        // h2 tile   128x32
    ushort_t* B0l = lds + 8192;        // k2t  3 strips of 32x32
    ushort_t* B1l = lds + 11264;       // rk2t 3 strips of 32x32

    const int tid  = threadIdx.x;
    const int lane = tid & 63;
    const int w    = tid >> 6;
    const int ln   = lane & 15;
    const int kg   = lane >> 4;
    const int wr   = w >> 1, wc = w & 1;

    const int m0 = blockIdx.y * 128;
    const int i0 = blockIdx.x * 32;

    const int crow = lane >> 2;
    const int ckof = (lane & 3) * 8;

    f32x4 acc0[4][3] = {};   // x-proj
    f32x4 acc1[4][3] = {};   // recurrent

    for (int k0 = 0; k0 < H_; k0 += 32) {
        #pragma unroll
        for (int c = w; c < 28; c += 4) {
            const ushort_t* g;
            ushort_t* l;
            if (c < 8) {
                g = s1b + (size_t)(m0 + c * 16 + crow) * H_ + k0 + ckof;
                l = A0l + c * 512;
            } else if (c < 16) {
                const int cc = c - 8;
                g = hb_cur + (size_t)(m0 + cc * 16 + crow) * H_ + k0 + ckof;
                l = A1l + cc * 512;
            } else if (c < 22) {
                const int idx = c - 16;
                g = k2t + (size_t)((idx >> 1) * H_ + i0 + (idx & 1) * 16 + crow) * H_ + k0 + ckof;
                l = B0l + idx * 512;
            } else {
                const int idx = c - 22;
                g = rk2t + (size_t)((idx >> 1) * H_ + i0 + (idx & 1) * 16 + crow) * H_ + k0 + ckof;
                l = B1l + idx * 512;
            }
#if HAVE_ASYNC
            gld_lds16(g, l);
#else
            *(bf16x8*)(l + lane * 8) = *(const bf16x8*)g;
#endif
        }
        __syncthreads();

        bf16x8 a0[4], a1[4], b0[3], b1[3];
        #pragma unroll
        for (int fm = 0; fm < 4; ++fm) {
            a0[fm] = *(const bf16x8*)(A0l + (wr * 64 + fm * 16 + ln) * 32 + kg * 8);
            a1[fm] = *(const bf16x8*)(A1l + (wr * 64 + fm * 16 + ln) * 32 + kg * 8);
        }
        #pragma unroll
        for (int g = 0; g < 3; ++g) {
            b0[g] = *(const bf16x8*)(B0l + g * 1024 + (wc * 16 + ln) * 32 + kg * 8);
            b1[g] = *(const bf16x8*)(B1l + g * 1024 + (wc * 16 + ln) * 32 + kg * 8);
        }

        #pragma unroll
        for (int fm = 0; fm < 4; ++fm)
            #pragma unroll
            for (int g = 0; g < 3; ++g) {
                acc0[fm][g] = __builtin_amdgcn_mfma_f32_16x16x32_bf16(
                    a0[fm], b0[g], acc0[fm][g], 0, 0, 0);
                acc1[fm][g] = __builtin_amdgcn_mfma_f32_16x16x32_bf16(
                    a1[fm], b1[g], acc1[fm][g], 0, 0, 0);
            }
        __syncthreads();
    }

    const int i = i0 + wc * 16 + ln;
    const float bxz = bx[i], bxr = bx[H_ + i], bxh = bx[2 * H_ + i];
    const float brz = br[i], brr = br[H_ + i], brh = br[2 * H_ + i];

    #pragma unroll
    for (int fm = 0; fm < 4; ++fm) {
        #pragma unroll
        for (int r = 0; r < 4; ++r) {
            const int b = m0 + wr * 64 + fm * 16 + kg * 4 + r;
            const int id = tgt[(size_t)b * T_ + t];
            const float hv = hf_cur[(size_t)b * H_ + i];
            float z  = sigmoidf_((acc0[fm][0][r] + bxz) + (acc1[fm][0][r] + brz));
            float rr = sigmoidf_((acc0[fm][1][r] + bxr) + (acc1[fm][1][r] + brr));
            float hh = tanhf((acc0[fm][2][r] + bxh) + rr * (acc1[fm][2][r] + brh));
            float hn = (id != 0) ? (z * hv + (1.0f - z) * hh) : hv;
            hf_nxt[(size_t)b * H_ + i] = hn;
            hb_nxt[(size_t)b * H_ + i] = __float2bfloat16(hn);
        }
    }
}

// ---------------------------------------------------------------------------
// Fused vocab projection + softmax. 16 rows/block, 256 threads.
// ---------------------------------------------------------------------------
__device__ __forceinline__ void softmax_write4(
    float ax, float ay, float az, float aw, float* __restrict__ outp, int cg)
{
    float m = fmaxf(fmaxf(ax, ay), fmaxf(az, aw));
    #pragma unroll
    for (int d = 16; d >= 1; d >>= 1) m = fmaxf(m, __shfl_xor(m, d));
    float ex = __expf(ax - m), ey = __expf(ay - m),
          ez = __expf(az - m), ew = __expf(aw - m);
    float s = ex + ey + ez + ew;
    #pragma unroll
    for (int d = 16; d >= 1; d >>= 1) s += __shfl_xor(s, d);
    float inv = 1.0f / s;
    float4 o; o.x = ex * inv; o.y = ey * inv; o.z = ez * inv; o.w = ew * inv;
    *(float4*)(outp + cg * 4) = o;
}

__global__ __launch_bounds__(256) void out_softmax(
    const float* __restrict__ h2, const float* __restrict__ Wv,
    const float* __restrict__ bv, float* __restrict__ out, int t)
{
    const int tid = threadIdx.x;
    const int cg = tid & 31;
    const int rg = tid >> 5;
    const int row0 = blockIdx.x * 16;

    __shared__ float hs[16][512];
    for (int idx = tid; idx < 16 * 512; idx += 256)
        hs[idx >> 9][idx & 511] = h2[(size_t)(row0 + (idx >> 9)) * 512 + (idx & 511)];
    __syncthreads();

    const int r0 = rg * 2;
    const float4 bvv = *(const float4*)(bv + cg * 4);
    float a0x = bvv.x, a0y = bvv.y, a0z = bvv.z, a0w = bvv.w;
    float a1x = bvv.x, a1y = bvv.y, a1z = bvv.z, a1w = bvv.w;

    #pragma unroll 4
    for (int k = 0; k < 512; ++k) {
        float4 wv = *(const float4*)(Wv + (size_t)k * V_ + cg * 4);
        float h0 = hs[r0][k], h1 = hs[r0 + 1][k];
        a0x += h0 * wv.x; a0y += h0 * wv.y; a0z += h0 * wv.z; a0w += h0 * wv.w;
        a1x += h1 * wv.x; a1y += h1 * wv.y; a1z += h1 * wv.z; a1w += h1 * wv.w;
    }

    softmax_write4(a0x, a0y, a0z, a0w, out + ((size_t)(row0 + r0) * T_ + t) * V_, cg);
    softmax_write4(a1x, a1y, a1z, a1w, out + ((size_t)(row0 + r0 + 1) * T_ + t) * V_, cg);
}

// ---------------------------------------------------------------------------
// Launch
// ---------------------------------------------------------------------------
extern "C" void kernel_launch(void* const* d_in, const int* in_sizes, int n_in,
                              void* d_out, int out_size, void* d_ws, size_t ws_size,
                              hipStream_t stream)
{
    const int*   tgt  = (const int*)  d_in[0];
    const float* enc  = (const float*)d_in[1];
    const float* Wi1  = (const float*)d_in[2];
    const float* Wi2  = (const float*)d_in[3];
    const float* emb  = (const float*)d_in[4];
    const float* k1   = (const float*)d_in[5];
    const float* rk1  = (const float*)d_in[6];
    const float* b1   = (const float*)d_in[7];
    const float* k2   = (const float*)d_in[8];
    const float* rk2  = (const float*)d_in[9];
    const float* b2   = (const float*)d_in[10];
    const float* Wv   = (const float*)d_in[11];
    const float* bv   = (const float*)d_in[12];
    float* out = (float*)d_out;

    // workspace layout (floats; ~31 MB total)
    // hf[buf][layer]: buf stride 2*BH, layer stride BH. Same for hb (bf16).
    float* ws  = (float*)d_ws;
    float* xe1 = ws;                                   // [V,3H]
    float* hf  = xe1 + (size_t)V_ * H3_;               // [2][2][B*H] fp32
    __hip_bfloat16* hb = (__hip_bfloat16*)(hf + (size_t)4 * BH_);  // [2][2][B*H] bf16
    __hip_bfloat16* rk1t = hb + (size_t)4 * BH_;       // [3H,H]
    __hip_bfloat16* k2t  = rk1t + (size_t)H3_ * H_;
    __hip_bfloat16* rk2t = k2t  + (size_t)H3_ * H_;

    dim3 blk(256);

    // one-time: weight transposes to bf16
    transpose_to_bf16<<<dim3(H3_ / 32, H_ / 32), blk, 0, stream>>>(rk1, rk1t, H_, H3_);
    transpose_to_bf16<<<dim3(H3_ / 32, H_ / 32), blk, 0, stream>>>(k2,  k2t,  H_, H3_);
    transpose_to_bf16<<<dim3(H3_ / 32, H_ / 32), blk, 0, stream>>>(rk2, rk2t, H_, H3_);

    // xe1 = embed_table @ k1 + b1[0]  (reassociated x1; gathered per (b,t))
    gemm_f32<<<dim3(H3_ / BN, V_ / BM), blk, 0, stream>>>(emb, k1, b1, xe1, V_, H3_, E_);
    // initial states into buffer 0: h01 -> hf[0][0], h02 -> hf[0][1]
    gemm_f32<<<dim3(H_ / BN, B_ / BM), blk, 0, stream>>>(enc, Wi1, nullptr, hf,       B_, H_, ENC_);
    gemm_f32<<<dim3(H_ / BN, B_ / BM), blk, 0, stream>>>(enc, Wi2, nullptr, hf + BH_, B_, H_, ENC_);
    f32_to_bf16_k<<<(2 * BH_) / 256, blk, 0, stream>>>(hf, hb, 2 * BH_);

    const dim3 fgrid(H_ / 32, B_ / 128);   // 16 x 16 = 256 blocks

    for (int t = 0; t < T_; ++t) {
        const int cur = t & 1, nxt = cur ^ 1;
        float* h1f_c = hf + (size_t)cur * 2 * BH_;
        float* h1f_n = hf + (size_t)nxt * 2 * BH_;
        float* h2f_c = h1f_c + BH_;
        float* h2f_n = h1f_n + BH_;
        __hip_bfloat16* h1b_c = hb + (size_t)cur * 2 * BH_;
        __hip_bfloat16* h1b_n = hb + (size_t)nxt * 2 * BH_;
        __hip_bfloat16* h2b_c = h1b_c + BH_;
        __hip_bfloat16* h2b_n = h1b_n + BH_;

        l1_fused<<<fgrid, blk, 0, stream>>>(
            tgt, t, xe1, (const ushort_t*)rk1t, b1 + H3_,
            h1f_c, (const ushort_t*)h1b_c, h1f_n, h1b_n);

        l2_fused<<<fgrid, blk, 0, stream>>>(
            tgt, t, (const ushort_t*)k2t, (const ushort_t*)rk2t, b2, b2 + H3_,
            (const ushort_t*)h1b_n, h2f_c, (const ushort_t*)h2b_c, h2f_n, h2b_n);

        out_softmax<<<dim3(B_ / 16), blk, 0, stream>>>(h2f_n, Wv, bv, out, t);
    }
}